// Round 8
// baseline (216.053 us; speedup 1.0000x reference)
//
#include <hip/hip_runtime.h>

#define LOG2E 1.44269504088896340736f
#define LN2   0.69314718055994530942f

typedef short bf8 __attribute__((ext_vector_type(8)));   // 8 bf16 = one 16x16x32 A/B frag (4 VGPRs)
typedef float f4  __attribute__((ext_vector_type(4)));   // 4 f32  = one 16x16 C/D frag
typedef float f2  __attribute__((ext_vector_type(2)));   // packed f32 pair -> v_pk_mul_f32

static __device__ __forceinline__ unsigned short f2bf_rne(float f) {
    unsigned u = __float_as_uint(f);
    u += 0x7FFFu + ((u >> 16) & 1u);
    return (unsigned short)(u >> 16);
}
// pack two f32 -> two bf16 (truncation; same numerics as all passing rounds)
static __device__ __forceinline__ unsigned pack_bf_trunc(float lo, float hi) {
    return __builtin_amdgcn_perm(__float_as_uint(hi), __float_as_uint(lo), 0x07060302u);
}

// MFMA via inline asm, all operands in arch VGPRs ("v" constraints).
static __device__ __forceinline__ f4 mfma_v(bf8 a, bf8 b, f4 c) {
    f4 d;
    asm volatile("v_mfma_f32_16x16x32_bf16 %0, %1, %2, %3"
                 : "=v"(d) : "v"(a), "v"(b), "v"(c));
    return d;
}
#define SB() __builtin_amdgcn_sched_barrier(0)

// ============================================================================
// Kernel 1: per-(batch, 64-step chunk) operator product, P fully in registers,
// SKEWED 4-group software pipeline.
//
//   Op_t = mask_t ? D_t * M^T : I,  D_t = diag(exp(em_t) * 2^-7), M = exp(tr)
//   P_c  = Op_{t0+63} ... Op_{t0}   (64x64), dumped bf16 as P^T.
//
// P's 4 column tiles (g = nt = 0..3) evolve independently. Per iteration the
// slot order  burst(g1) pack(g0) burst(g2) pack(g1) burst(g3) pack(g2)
// burst(g0,s+1) pack(g3)  (pinned with sched_barrier(0)) lets each pack's
// VALU execute under the next group's 8-MFMA burst: matrix pipe ~continuously
// busy instead of the alternate-and-stall lockstep of r3-r7 (elapsed was
// matrix-busy + VALU-busy, pipes never overlapped). Each pack is >= one full
// burst (~128 cy >> 18 wait states) after its acc's last MFMA: no nops needed.
// Branchless mask via cndmask select (inactive step == identity, numerics
// identical to the branchy version). Two acc banks ping-pong (g0/g2, g1/g3).
//
// __launch_bounds__(64, 2): min 2 waves/EU -> 256-reg budget so the ~135-reg
// working set stays in ARCH VGPRs. r3-r7's VGPR_Count=60 (< afr+bfr alone!)
// proved the allocator was targeting high occupancy and shuttling the state
// through AGPRs with v_accvgpr copies at every use — the real VALU bloat.
//
// Layout (verified r3-r7, absmax 0): B-frag bfr[kt][nt][j] = P[32kt+8q+j]
// [16nt+nl]; output tile mt -> global rows g(mt,4q+r)=32(mt>>1)+8q+4(mt&1)+r,
// so tile mt's scaled/packed output IS dword-half (mt&1) of bfr[mt>>1][nt] in
// the same lane (row permutation folded into the A-fragments at setup).
// ============================================================================
__global__ __launch_bounds__(64, 2)
void crf_scan(const int* __restrict__ yg, const float* __restrict__ em,
              const float* __restrict__ tr, unsigned short* __restrict__ Pg)
{
    constexpr int T = 1024;
    const int c = blockIdx.x, b = blockIdx.y;
    const int lane = threadIdx.x, nl = lane & 15, q = lane >> 4;

    __shared__ __align__(16) float d_sh[64];

    // ---- A-fragments of M^T with permuted rows (constant) ----
    bf8 afr[4][2];
    #pragma unroll
    for (int mt = 0; mt < 4; ++mt) {
        const int g = 32 * (mt >> 1) + 8 * (nl >> 2) + 4 * (mt & 1) + (nl & 3);
        #pragma unroll
        for (int ka = 0; ka < 2; ++ka) {
            bf8 v;
            #pragma unroll
            for (int j = 0; j < 8; ++j) {
                const int k = 32 * ka + 8 * q + j;
                v[j] = (short)f2bf_rne(exp2f(tr[k * 64 + g] * LOG2E));
            }
            afr[mt][ka] = v;
        }
    }

    // ---- P = I in B-fragments: bfr[kt][nt][j] = (32kt+8q+j == 16nt+nl) ----
    bf8 bfr[2][4];
    #pragma unroll
    for (int kt = 0; kt < 2; ++kt)
        #pragma unroll
        for (int nt = 0; nt < 4; ++nt) {
            bf8 v;
            #pragma unroll
            for (int j = 0; j < 8; ++j)
                v[j] = (short)((32 * kt + 8 * q + j == 16 * nt + nl) ? 0x3F80 : 0);
            bfr[kt][nt] = v;
        }

    const f4 zc = (f4)(0.0f);

    const int t0 = 1 + 64 * c;
    const int nsteps = (c == 15) ? 63 : 64;
    const float* emb = em + (size_t)b * T * 64;

    int tl = t0 + lane; if (tl > T - 1) tl = T - 1;
    const unsigned long long msk = __ballot(lane < nsteps && yg[b * T + tl] != 0);

    // 8 MFMAs into bank ACC for column tile G (2-deep K=64 chain per mt)
#define BURST(ACC, G)                                                        \
    { _Pragma("unroll")                                                      \
      for (int mt = 0; mt < 4; ++mt) {                                       \
          f4 t4 = mfma_v(afr[mt][0], bfr[0][G], zc);                         \
          ACC[mt] = mfma_v(afr[mt][1], bfr[1][G], t4);                       \
      } }

    // diag-scale + bf16-pack + mask-select, bank ACC -> bfr[*][G]
#define PACK(ACC, G, ACT)                                                    \
    { _Pragma("unroll")                                                      \
      for (int kt = 0; kt < 2; ++kt) {                                       \
          f2 a0, a1, b0, b1;                                                 \
          a0[0] = ACC[2*kt  ][0]; a0[1] = ACC[2*kt  ][1];                    \
          a1[0] = ACC[2*kt  ][2]; a1[1] = ACC[2*kt  ][3];                    \
          b0[0] = ACC[2*kt+1][0]; b0[1] = ACC[2*kt+1][1];                    \
          b1[0] = ACC[2*kt+1][2]; b1[1] = ACC[2*kt+1][3];                    \
          a0 *= dp[2*kt  ][0];  a1 *= dp[2*kt  ][1];   /* v_pk_mul_f32 */    \
          b0 *= dp[2*kt+1][0];  b1 *= dp[2*kt+1][1];                         \
          union { uint4 uu; bf8 v8; } wv, od;                                \
          od.v8 = bfr[kt][G];                                                \
          const unsigned nx = pack_bf_trunc(a0[0], a0[1]);                   \
          const unsigned ny = pack_bf_trunc(a1[0], a1[1]);                   \
          const unsigned nz = pack_bf_trunc(b0[0], b0[1]);                   \
          const unsigned nw = pack_bf_trunc(b1[0], b1[1]);                   \
          wv.uu.x = (ACT) ? nx : od.uu.x;                                    \
          wv.uu.y = (ACT) ? ny : od.uu.y;                                    \
          wv.uu.z = (ACT) ? nz : od.uu.z;                                    \
          wv.uu.w = (ACT) ? nw : od.uu.w;                                    \
          bfr[kt][G] = wv.v8;                                                \
      } }

#define LOAD_DP()                                                            \
    { _Pragma("unroll")                                                      \
      for (int mt = 0; mt < 4; ++mt) {                                       \
          const float* dsrc = &d_sh[32 * (mt >> 1) + 4 * (mt & 1) + 8 * q];  \
          dp[mt][0] = *(const f2*)&dsrc[0];                                  \
          dp[mt][1] = *(const f2*)&dsrc[2];                                  \
      } }

    // ---- prologue: d(0), first g0 burst ----
    float ldc = emb[t0 * 64 + lane];
    d_sh[lane] = exp2f(ldc * LOG2E - 7.0f);   // single wave: DS in-order
    f2 dp[4][2];
    LOAD_DP();
    f4 aA[4], aB[4];
    BURST(aA, 0);                              // step 0, group 0

    for (int s = 0; s < nsteps; ++s) {
        int tn = t0 + s + 1; if (tn > T - 1) tn = T - 1;
        const float ldn = emb[tn * 64 + lane];            // emission prefetch
        const bool act = (msk >> s) & 1ull;
        SB(); BURST(aB, 1);                    // g1(s)     | matrix
        SB(); PACK(aA, 0, act);                // g0(s)     | VALU under g1
        SB(); BURST(aA, 2);                    // g2(s)
        SB(); PACK(aB, 1, act);                // g1(s) under g2
        SB(); BURST(aB, 3);                    // g3(s)
        SB(); PACK(aA, 2, act);                // g2(s) under g3
        SB(); BURST(aA, 0);                    // g0(s+1) — bfr[*][0] packed above
        SB(); PACK(aB, 3, act);                // g3(s) under g0(s+1)
        SB();
        ldc = ldn;                             // d(s+1) for next iter's packs
        d_sh[lane] = exp2f(ldc * LOG2E - 7.0f);
        LOAD_DP();
    }
#undef BURST
#undef PACK
#undef LOAD_DP

    // ---- dump P^T: Pg[(b*16+c)*4096 + n*64 + i] = P_c[i][n],
    //      n = 16nt+nl, i = 32kt+8q+j (j contiguous -> 16B stores) ----
    unsigned short* pg = Pg + ((size_t)(b * 16 + c) << 12);
    #pragma unroll
    for (int nt = 0; nt < 4; ++nt)
        #pragma unroll
        for (int kt = 0; kt < 2; ++kt)
            *(uint4*)(pg + (16 * nt + nl) * 64 + 32 * kt + 8 * q) =
                *(const uint4*)&bfr[kt][nt];
}

// ============================================================================
// Kernel 2: per-batch combine, 4 waves/block (unchanged — profiling across
// r0-r7 shows the non-scan residual is invariant harness reset overhead,
// not this kernel).
// ============================================================================
__global__ __attribute__((amdgpu_flat_work_group_size(256, 256)))
void crf_combine(const int* __restrict__ yg, const float* __restrict__ em,
                 const float* __restrict__ tr, const unsigned short* __restrict__ Pg,
                 float* __restrict__ out)
{
    constexpr int T = 1024;
    const int b = blockIdx.x, tid = threadIdx.x;
    const int w = tid >> 6, j = tid & 63;

    __shared__ __align__(16) float v_sh[64];
    __shared__ float red[3][4];

    float ep = 0.f, tp = 0.f; int cnt = 0;
    float v = 0.f, L = 0.f, vs = 0.f;

    if (w == 0) {
        const float e0 = em[(size_t)b * T * 64 + j];
        float M0 = e0;
        #pragma unroll
        for (int o = 32; o > 0; o >>= 1) M0 = fmaxf(M0, __shfl_xor(M0, o, 64));
        v = exp2f((e0 - M0) * LOG2E);
        L = M0;

        const unsigned short* row = Pg + ((size_t)(b * 16) << 12) + j * 64; // col j of P_c
        uint4 pA[8], pB[8];
        #pragma unroll
        for (int r = 0; r < 8; ++r) pA[r] = *(const uint4*)(row + r * 8);

#define CHUNK_STEP(CUR, NXT, CIDX)                                                 \
        do {                                                                       \
            if ((CIDX) + 1 < 16) {  /* prefetch next chunk: independent of v */    \
                const unsigned short* rn = row + ((size_t)((CIDX) + 1) << 12);     \
                _Pragma("unroll")                                                  \
                for (int r = 0; r < 8; ++r) NXT[r] = *(const uint4*)(rn + r * 8);  \
            }                                                                      \
            v_sh[j] = v;                            /* single wave: in-order DS */ \
            float s0 = 0.f, s1 = 0.f, s2 = 0.f, s3 = 0.f;                          \
            _Pragma("unroll")                                                      \
            for (int r = 0; r < 8; ++r) {                                          \
                const uint4 qq = CUR[r];                                           \
                const float* vp = &v_sh[r * 8];                                    \
                s0 = fmaf(__uint_as_float(qq.x << 16),         vp[0], s0);         \
                s1 = fmaf(__uint_as_float(qq.x & 0xFFFF0000u), vp[1], s1);         \
                s2 = fmaf(__uint_as_float(qq.y << 16),         vp[2], s2);         \
                s3 = fmaf(__uint_as_float(qq.y & 0xFFFF0000u), vp[3], s3);         \
                s0 = fmaf(__uint_as_float(qq.z << 16),         vp[4], s0);         \
                s1 = fmaf(__uint_as_float(qq.z & 0xFFFF0000u), vp[5], s1);         \
                s2 = fmaf(__uint_as_float(qq.w << 16),         vp[6], s2);         \
                s3 = fmaf(__uint_as_float(qq.w & 0xFFFF0000u), vp[7], s3);         \
            }                                                                      \
            float s = (s0 + s1) + (s2 + s3);                                       \
            const unsigned sb =                                                    \
                (unsigned)__builtin_amdgcn_readlane((int)__float_as_uint(s), 0);   \
            const int ef = (int)((sb >> 23) & 0xFF);                               \
            if (ef > 0 && ef < 255 && ef != 127) {  /* exact-pow2 re-center */     \
                const int E = ef - 127;                                            \
                s *= __uint_as_float((unsigned)(127 - E) << 23);                   \
                L += (float)E * LN2;                                               \
            }                                                                      \
            v = s;                                                                 \
        } while (0)

        for (int cc = 0; cc < 16; cc += 2) {
            CHUNK_STEP(pA, pB, cc);
            CHUNK_STEP(pB, pA, cc + 1);
        }
#undef CHUNK_STEP

        vs = v;
        #pragma unroll
        for (int o = 32; o > 0; o >>= 1) vs += __shfl_xor(vs, o, 64);
    } else {
        // ---- scores + unmasked-step count, waves 1..3 (stride 192 over t) ----
        const int* yb = yg + b * T;
        const int wt = tid - 64;                      // 0..191
        for (int t = 1 + wt; t < T; t += 192) {
            const int yt = yb[t];
            if (yt != 0) {
                ++cnt;
                tp += tr[yb[t - 1] * 64 + yt];
                ep += em[((size_t)b * T + t) * 64 + yt];
            }
        }
        if (tid == 64) {
            const int y0 = yb[0];
            if (y0 != 0) ep += em[(size_t)b * T * 64 + y0];
        }
        #pragma unroll
        for (int o = 32; o > 0; o >>= 1) {
            ep  += __shfl_xor(ep, o, 64);
            tp  += __shfl_xor(tp, o, 64);
            cnt += __shfl_xor(cnt, o, 64);
        }
        if (j == 0) { red[0][w] = ep; red[1][w] = tp; red[2][w] = (float)cnt; }
    }
    __syncthreads();

    if (tid == 0) {
        const float eps = red[0][1] + red[0][2] + red[0][3];
        const float tps = red[1][1] + red[1][2] + red[1][3];
        const float cs  = red[2][1] + red[2][2] + red[2][3];
        const float logz = L + 7.0f * LN2 * cs + __log2f(vs) * LN2;
        atomicAdd(out, (eps + tps - logz) * (-1.0f / 256.0f));
    }
}

extern "C" void kernel_launch(void* const* d_in, const int* in_sizes, int n_in,
                              void* d_out, int out_size, void* d_ws, size_t ws_size,
                              hipStream_t stream) {
    const int*   y  = (const int*)d_in[0];
    const float* em = (const float*)d_in[1];
    const float* tr = (const float*)d_in[2];
    float* out = (float*)d_out;
    unsigned short* Pg = (unsigned short*)d_ws;   // needs 256*16*4096*2 = 32 MB

    hipMemsetAsync(out, 0, sizeof(float), stream);
    crf_scan<<<dim3(16, 256), dim3(64), 0, stream>>>(y, em, tr, Pg);
    crf_combine<<<dim3(256), dim3(256), 0, stream>>>(y, em, tr, Pg, out);
}